// Round 7
// baseline (3708.591 us; speedup 1.0000x reference)
//
#include <hip/hip_runtime.h>
#include <cstdint>

#define N_PTS 100000
#define N_EDGE 800000
#define N_ITEMS (N_EDGE + N_PTS)   // real edges + self-loops
#define IMG_W 1216
#define IMG_H 240
#define OW 304
#define OH 60
#define CHUNK 32
#define BIN_BLOCKS 391   // ceil(N_PTS/256)
#define SENT 0x7fffffff

typedef _Float16 f16;
typedef _Float16 f16x8 __attribute__((ext_vector_type(8)));
typedef float f32x4 __attribute__((ext_vector_type(4)));

// ---------------- per-node kernel: A[n] = X[n]@w1_x + pos[n]@w1_p + b1 (f16) ----------------
template<int DIN_X, int DOUT>
__global__ __launch_bounds__(256)
void node_kernel(const float* __restrict__ X, const float* __restrict__ pos,
                 const float* __restrict__ w1, const float* __restrict__ b1,
                 f16* __restrict__ A)
{
    constexpr int M = 8;
    constexpr int R = 256 / DOUT;
    constexpr int RR = (R < 1) ? 1 : R;
    constexpr int MN = M / RR;
    const int tid = threadIdx.x;
    const int c = tid % DOUT;
    const int r = tid / DOUT;
    const long n0 = (long)blockIdx.x * M;

    __shared__ float xs[M][DIN_X];
    __shared__ float ps[M][4];

    for (int idx = tid; idx < M * DIN_X; idx += 256) {
        int m = idx / DIN_X, k = idx % DIN_X;
        long n = n0 + m;
        xs[m][k] = (n < N_PTS) ? X[n * DIN_X + k] : 0.0f;
    }
    for (int idx = tid; idx < M * 3; idx += 256) {
        int m = idx / 3, k = idx % 3;
        long n = n0 + m;
        ps[m][k] = (n < N_PTS) ? pos[n * 3 + k] : 0.0f;
    }
    __syncthreads();

    float acc[MN];
#pragma unroll
    for (int mi = 0; mi < MN; ++mi) acc[mi] = b1[c];

    for (int k = 0; k < DIN_X; ++k) {
        float wv = w1[k * DOUT + c];
#pragma unroll
        for (int mi = 0; mi < MN; ++mi)
            acc[mi] += xs[r * MN + mi][k] * wv;
    }
#pragma unroll
    for (int k = 0; k < 3; ++k) {
        float wv = w1[(DIN_X + k) * DOUT + c];
#pragma unroll
        for (int mi = 0; mi < MN; ++mi)
            acc[mi] += ps[r * MN + mi][k] * wv;
    }
#pragma unroll
    for (int mi = 0; mi < MN; ++mi) {
        long n = n0 + r * MN + mi;
        if (n < N_PTS) A[n * DOUT + c] = (f16)acc[mi];
    }
}

// ---------------- w2 -> f16 transpose: w2t[n*D+k] = (f16)w2[k*D+n] ----------------
__global__ void cvt_w2(const float* __restrict__ w2, f16* __restrict__ w2t, int D)
{
    int i = blockIdx.x * 256 + threadIdx.x;
    if (i >= D * D) return;
    int n = i / D, k = i % D;
    w2t[i] = (f16)w2[k * D + n];
}

// ---------------- counting sort of (edges + self-loops) by dst ----------------
__global__ void init_hist_kernel(int* __restrict__ hist)
{
    int i = blockIdx.x * 256 + threadIdx.x;
    if (i < N_PTS) hist[i] = 1;   // self-loop
}

__global__ void hist_kernel(const int* __restrict__ ei, int* __restrict__ hist)
{
    int e = blockIdx.x * 256 + threadIdx.x;
    if (e < N_EDGE) atomicAdd(&hist[ei[N_EDGE + e]], 1);
}

__global__ void bsum_kernel(const int* __restrict__ hist, int* __restrict__ bsum)
{
    __shared__ int s[256];
    int i = blockIdx.x * 256 + threadIdx.x;
    s[threadIdx.x] = (i < N_PTS) ? hist[i] : 0;
    __syncthreads();
    for (int off = 128; off > 0; off >>= 1) {
        if (threadIdx.x < off) s[threadIdx.x] += s[threadIdx.x + off];
        __syncthreads();
    }
    if (threadIdx.x == 0) bsum[blockIdx.x] = s[0];
}

__global__ void scan_bsum_kernel(int* __restrict__ bsum)
{
    __shared__ int s[512];
    int t = threadIdx.x;
    int v = (t < BIN_BLOCKS) ? bsum[t] : 0;
    s[t] = v;
    __syncthreads();
    for (int off = 1; off < 512; off <<= 1) {
        int u = (t >= off) ? s[t - off] : 0;
        __syncthreads();
        s[t] += u;
        __syncthreads();
    }
    if (t < BIN_BLOCKS) bsum[t] = s[t] - v;   // exclusive
}

__global__ void rowptr_kernel(const int* __restrict__ hist, const int* __restrict__ bsum,
                              int* __restrict__ woff)
{
    __shared__ int s[256];
    int i = blockIdx.x * 256 + threadIdx.x;
    int v = (i < N_PTS) ? hist[i] : 0;
    s[threadIdx.x] = v;
    __syncthreads();
    for (int off = 1; off < 256; off <<= 1) {
        int u = (threadIdx.x >= off) ? s[threadIdx.x - off] : 0;
        __syncthreads();
        s[threadIdx.x] += u;
        __syncthreads();
    }
    if (i < N_PTS) woff[i] = bsum[blockIdx.x] + s[threadIdx.x] - v;  // exclusive
}

// scatter real edges and self-loops; afterwards woff[i] = row_ptr[i+1]
__global__ void scatter_edges_kernel(const int* __restrict__ ei, int* __restrict__ woff,
                                     int* __restrict__ srcS, int* __restrict__ dstS)
{
    int e = blockIdx.x * 256 + threadIdx.x;
    if (e >= N_ITEMS) return;
    int s, d;
    if (e < N_EDGE) { s = ei[e]; d = ei[N_EDGE + e]; }
    else            { s = d = e - N_EDGE; }
    int p = atomicAdd(&woff[d], 1);
    srcS[p] = s;
    dstS[p] = d;
}

// ---------------- MFMA segment-reduce message kernel (atomic-free) ----------------
// Each wave owns 8 consecutive dst nodes; iterates their contiguous sorted items
// (incl. self-loops) in 16-row chunks. h = relu(A[src] - pos[dst]·w1p);
// g = h @ w2 + b2 via mfma_f32_16x16x32_f16; segmented max over sorted rows
// done in-register (per-lane suffix + 3-step cross-kg chain + cross-chunk carry).
// Exactly ONE plain store per (dst, col).
// Fragment layouts: A row=lane&15, k=(lane>>4)*8+j ; B col=lane&15, same k ;
// C/D col=lane&15, row=(lane>>4)*4+reg.
template<int D>
__global__ __launch_bounds__(256)
void gemm_seg_kernel(const int* __restrict__ srcS, const int* __restrict__ dstS,
                     const int* __restrict__ rend,   // rend[i] = row_ptr[i+1]
                     const f16* __restrict__ A, const float* __restrict__ pos,
                     const float* __restrict__ w1p, const f16* __restrict__ w2t,
                     const float* __restrict__ b2, float* __restrict__ OUT)
{
    constexpr int KB = D / 32;
    constexpr int NB = D / 16;
    const int tid = threadIdx.x;
    const int wave = tid >> 6;
    const int lane = tid & 63;
    const int row = lane & 15;          // chunk row this lane loads / out col within nb
    const int kg = lane >> 4;
    const int g0 = (blockIdx.x * 4 + wave) * 8;   // first owned dst
    const int start = (g0 == 0) ? 0 : rend[g0 - 1];
    const int end = rend[g0 + 7];
    const int nch = (end - start + 15) >> 4;

    int cd = -1;                 // carry dst (run containing last row of prev chunk)
    float cm[NB];
#pragma unroll
    for (int i = 0; i < NB; ++i) cm[i] = -INFINITY;

    for (int ch = 0; ch < nch; ++ch) {
        const int base = start + ch * 16;
        const int e = base + row;
        const bool okr = (e < end);
        const int s_ld = okr ? srcS[e] : 0;
        const int d_cmp = okr ? dstS[e] : SENT;
        const int d_safe = okr ? d_cmp : 0;
        const float qx = pos[(long)d_safe * 3 + 0];
        const float qy = pos[(long)d_safe * 3 + 1];
        const float qz = pos[(long)d_safe * 3 + 2];

        // A fragments (one edge row per lane, kg-th col slice)
        f16x8 pa[KB];
#pragma unroll
        for (int kb = 0; kb < KB; ++kb) {
            const int c0 = kb * 32 + kg * 8;
            f16x8 a = *(const f16x8*)&A[(long)s_ld * D + c0];
            f16x8 h;
#pragma unroll
            for (int j = 0; j < 8; ++j) {
                float wx = w1p[c0 + j];
                float wy = w1p[D + c0 + j];
                float wz = w1p[2 * D + c0 + j];
                h[j] = (f16)fmaxf((float)a[j] - (qx * wx + qy * wy + qz * wz), 0.0f);
            }
            pa[kb] = h;
        }

        // chunk control (nb-independent)
        int ddv[4];
#pragma unroll
        for (int reg = 0; reg < 4; ++reg) ddv[reg] = __shfl(d_cmp, kg * 4 + reg);
        const int d_last = __shfl(d_cmp, 15);
        const int d_row0 = __shfl(d_cmp, 0);
        const int prev3 = __shfl(d_cmp, (kg > 0) ? (kg * 4 - 1) : 0);
        const bool e01 = (ddv[1] == ddv[0]);
        const bool e12 = (ddv[2] == ddv[1]);
        const bool e23 = (ddv[3] == ddv[2]);
        const bool e02 = e01 && e12;
        const bool e03 = e02 && e23;
        const int Fs = e03 ? 1 : 0;
        const int d0n = __shfl(ddv[0], lane + 16);
        const int Fn = __shfl(Fs, lane + 16);
        const bool connect = (kg < 3) && (ddv[3] == d0n);
        const bool hd0 = (kg == 0) || (ddv[0] != prev3);
        const bool merge0 = (kg == 0) && (cd == ddv[0]);
        const bool stale = (cd >= 0) && (cd != SENT) && (cd != d_row0);
        const bool ccont = (cd == d_last);   // (sorted => implies whole chunk same dst)

#pragma unroll
        for (int nb = 0; nb < NB; ++nb) {
            const int col = nb * 16 + row;
            // flush carry whose run ended exactly at the previous chunk boundary
            if (stale && kg == 0) OUT[(long)cd * D + col] = cm[nb];

            f32x4 acc = {0.0f, 0.0f, 0.0f, 0.0f};
#pragma unroll
            for (int kb = 0; kb < KB; ++kb) {
                f16x8 pb = *(const f16x8*)&w2t[(long)(nb * 16 + row) * D + kb * 32 + kg * 8];
                acc = __builtin_amdgcn_mfma_f32_16x16x32_f16(pa[kb], pb, acc, 0, 0, 0);
            }
            const float bb = b2[col];
            const float v0 = acc[0] + bb, v1 = acc[1] + bb, v2 = acc[2] + bb, v3 = acc[3] + bb;
            // per-lane segmented suffix max
            const float s3 = v3;
            const float s2 = e23 ? fmaxf(v2, s3) : v2;
            const float s1 = e12 ? fmaxf(v1, s2) : v1;
            const float s0 = e01 ? fmaxf(v0, s1) : v0;
            // per-lane prefix max of dd[0]'s run
            float P = v0;
            P = e01 ? fmaxf(P, v1) : P;
            P = e02 ? fmaxf(P, v2) : P;
            P = e03 ? fmaxf(P, v3) : P;
            // cross-kg tail extension (3-step chain from kg=3 upward)
            float T = -INFINITY;
#pragma unroll
            for (int it = 0; it < 3; ++it) {
                float Pn = __shfl(P, lane + 16);
                float Tn = __shfl(T, lane + 16);
                T = connect ? fmaxf(Pn, Fn ? Tn : -INFINITY) : T;
            }
            const float x0 = e03 ? fmaxf(s0, T) : s0;
            const float x1 = (e12 && e23) ? fmaxf(s1, T) : s1;
            const float x2 = e23 ? fmaxf(s2, T) : s2;
            const float x3 = fmaxf(s3, T);
            // emit closed runs at their head rows (plain stores; exclusive ownership)
            if (hd0 && ddv[0] != d_last) {
                float val = x0;
                if (merge0) val = fmaxf(val, cm[nb]);
                OUT[(long)ddv[0] * D + col] = val;
            }
            if (!e01 && ddv[1] != d_last) OUT[(long)ddv[1] * D + col] = x1;
            if (!e12 && ddv[2] != d_last) OUT[(long)ddv[2] * D + col] = x2;
            if (!e23 && ddv[3] != d_last) OUT[(long)ddv[3] * D + col] = x3;
            // carry update: max over rows with dst == d_last
            float m = -INFINITY;
            if (ddv[0] == d_last) m = v0;
            if (ddv[1] == d_last) m = fmaxf(m, v1);
            if (ddv[2] == d_last) m = fmaxf(m, v2);
            if (ddv[3] == d_last) m = fmaxf(m, v3);
            m = fmaxf(m, __shfl_xor(m, 16));
            m = fmaxf(m, __shfl_xor(m, 32));
            cm[nb] = (ccont) ? fmaxf(cm[nb], m) : m;
        }
        cd = d_last;
    }
    // final carry flush
    if (kg == 0 && cd >= 0 && cd != SENT) {
#pragma unroll
        for (int nb = 0; nb < NB; ++nb)
            OUT[(long)cd * D + nb * 16 + row] = cm[nb];
    }
}

// ---------------- projection ----------------
__global__ void proj_kernel(const float* __restrict__ pos, const float* __restrict__ proj,
                            const int* __restrict__ img_h, const int* __restrict__ img_w,
                            int* __restrict__ pix)
{
    int n = blockIdx.x * blockDim.x + threadIdx.x;
    if (n >= N_PTS) return;
    float px = pos[n * 3 + 0], py = pos[n * 3 + 1], pz = pos[n * 3 + 2];
    float h0 = proj[0] * px + proj[1] * py + proj[2]  * pz + proj[3];
    float h1 = proj[4] * px + proj[5] * py + proj[6]  * pz + proj[7];
    float h2 = proj[8] * px + proj[9] * py + proj[10] * pz + proj[11];
    int off_u = img_w[0] - IMG_W;
    int off_v = img_h[0] - IMG_H;
    int ui = (int)(short)(h0 / h2) - off_u;   // int16 truncation semantics
    int vi = (int)(short)(h1 / h2) - off_v;
    bool valid = (ui >= 0) && (vi >= 0) && (ui < IMG_W) && (vi < IMG_H);
    pix[n] = valid ? (ui * IMG_H + vi) : -1;
}

// ---------------- scatter-add (pixel-major, CHUNK channels) ----------------
__global__ __launch_bounds__(256)
void scatter_kernel(const float* __restrict__ H, const int* __restrict__ pix,
                    float* __restrict__ img, int cbase)
{
    long g = (long)blockIdx.x * blockDim.x + threadIdx.x;
    if (g >= (long)N_PTS * CHUNK) return;
    int n = (int)(g / CHUNK);
    int c = (int)(g % CHUNK);
    int p = pix[n];
    if (p < 0) return;
    atomicAdd(&img[(long)p * CHUNK + c], H[(long)n * 256 + cbase + c]);
}

// ---------------- 4x4 max-pool ----------------
__global__ __launch_bounds__(CHUNK)
void pool_kernel(const float* __restrict__ img, float* __restrict__ out, int cbase)
{
    int cell = blockIdx.x;
    int wc = cell / OH, hc = cell % OH;
    int c = threadIdx.x;
    float mx = -INFINITY;
#pragma unroll
    for (int i = 0; i < 4; ++i)
#pragma unroll
        for (int j = 0; j < 4; ++j) {
            long p = (long)(wc * 4 + i) * IMG_H + (hc * 4 + j);
            mx = fmaxf(mx, img[p * CHUNK + c]);
        }
    out[(long)(cbase + c) * (OW * OH) + wc * OH + hc] = mx;
}

extern "C" void kernel_launch(void* const* d_in, const int* in_sizes, int n_in,
                              void* d_out, int out_size, void* d_ws, size_t ws_size,
                              hipStream_t stream)
{
    const float* x     = (const float*)d_in[0];
    const float* pos   = (const float*)d_in[1];
    const int*   ei    = (const int*)d_in[2];
    const float* proj  = (const float*)d_in[4];
    const int*   img_h = (const int*)d_in[5];
    const int*   img_w = (const int*)d_in[6];
    const float* w1_1 = (const float*)d_in[7];
    const float* b1_1 = (const float*)d_in[8];
    const float* w2_1 = (const float*)d_in[9];
    const float* b2_1 = (const float*)d_in[10];
    const float* w1_2 = (const float*)d_in[11];
    const float* b1_2 = (const float*)d_in[12];
    const float* w2_2 = (const float*)d_in[13];
    const float* b2_2 = (const float*)d_in[14];
    const float* w1_3 = (const float*)d_in[15];
    const float* b1_3 = (const float*)d_in[16];
    const float* w2_3 = (const float*)d_in[17];
    const float* b2_3 = (const float*)d_in[18];
    float* out = (float*)d_out;

    // ws layout (byte offsets), lifetime-aliased; peak = 162.3 MB:
    //   HH  @ 0           : N*256*4 = 102,400,000
    //   F1  @ 0           : N*128*4 =  51,200,000
    //   F0  @ 51,200,000  : N*64*4  =  25,600,000
    //   A12 @ 76,800,000  : N*128*2 =  25,600,000
    //   A3  @ 102,400,000 : N*256*2 =  51,200,000
    //   img @ 102,400,000 : 1216*240*32*4 = 37,355,520  [aliases A3 after edge3]
    //   pix @ 153,600,000 : 400,000
    //   w2t3 @ 154,000,000: 131,072 ; w2t2 @ 154,131,072: 32,768 ; w2t1 @ 154,163,840: 8,192
    //   srcS @ 154,200,000: 3,600,000 ; dstS @ 157,800,000: 3,600,000
    //   hist @ 161,400,000: 400,000 ; woff @ 161,800,000: 400,000 ; bsum @ 162,200,000: 2,048
    if (ws_size < 162300000ull) return;
    char* ws = (char*)d_ws;
    float* HH   = (float*)(ws + 0);
    float* F1   = (float*)(ws + 0);
    float* F0   = (float*)(ws + 51200000);
    f16*   A12  = (f16*)(ws + 76800000);
    f16*   A3   = (f16*)(ws + 102400000);
    float* img  = (float*)(ws + 102400000);
    int*   pix  = (int*)(ws + 153600000);
    f16*   w2t3 = (f16*)(ws + 154000000);
    f16*   w2t2 = (f16*)(ws + 154131072);
    f16*   w2t1 = (f16*)(ws + 154163840);
    int*   srcS = (int*)(ws + 154200000);
    int*   dstS = (int*)(ws + 157800000);
    int*   hist = (int*)(ws + 161400000);
    int*   woff = (int*)(ws + 161800000);
    int*   bsum = (int*)(ws + 162200000);

    const int NODE_BLOCKS = N_PTS / 8;            // 12500
    const int SEG_BLOCKS  = N_PTS / 32;           // 3125 (4 waves x 8 dsts)
    const int E256  = (N_EDGE + 255) / 256;       // 3125
    const int I256  = (N_ITEMS + 255) / 256;      // 3516

    // ---- sort (edges + self-loops) by dst; woff becomes row_ptr[i+1] ----
    init_hist_kernel<<<BIN_BLOCKS, 256, 0, stream>>>(hist);
    hist_kernel<<<E256, 256, 0, stream>>>(ei, hist);
    bsum_kernel<<<BIN_BLOCKS, 256, 0, stream>>>(hist, bsum);
    scan_bsum_kernel<<<1, 512, 0, stream>>>(bsum);
    rowptr_kernel<<<BIN_BLOCKS, 256, 0, stream>>>(hist, bsum, woff);
    scatter_edges_kernel<<<I256, 256, 0, stream>>>(ei, woff, srcS, dstS);

    // prep: transposed f16 weights + projection
    cvt_w2<<<(64 * 64 + 255) / 256, 256, 0, stream>>>(w2_1, w2t1, 64);
    cvt_w2<<<(128 * 128 + 255) / 256, 256, 0, stream>>>(w2_2, w2t2, 128);
    cvt_w2<<<(256 * 256 + 255) / 256, 256, 0, stream>>>(w2_3, w2t3, 256);
    proj_kernel<<<(N_PTS + 255) / 256, 256, 0, stream>>>(pos, proj, img_h, img_w, pix);

    // layer 1 (din 4 -> 64)
    node_kernel<4, 64><<<NODE_BLOCKS, 256, 0, stream>>>(x, pos, w1_1, b1_1, A12);
    gemm_seg_kernel<64><<<SEG_BLOCKS, 256, 0, stream>>>(srcS, dstS, woff, A12, pos, w1_1 + 4 * 64, w2t1, b2_1, F0);

    // layer 2 (64 -> 128)
    node_kernel<64, 128><<<NODE_BLOCKS, 256, 0, stream>>>(F0, pos, w1_2, b1_2, A12);
    gemm_seg_kernel<128><<<SEG_BLOCKS, 256, 0, stream>>>(srcS, dstS, woff, A12, pos, w1_2 + 64 * 128, w2t2, b2_2, F1);

    // layer 3 (128 -> 256)
    node_kernel<128, 256><<<NODE_BLOCKS, 256, 0, stream>>>(F1, pos, w1_3, b1_3, A3);
    gemm_seg_kernel<256><<<SEG_BLOCKS, 256, 0, stream>>>(srcS, dstS, woff, A3, pos, w1_3 + 128 * 256, w2t3, b2_3, HH);

    // scatter + pool in 32-channel chunks
    for (int cb = 0; cb < 256; cb += CHUNK) {
        hipMemsetAsync(img, 0, (size_t)IMG_W * IMG_H * CHUNK * 4, stream);
        scatter_kernel<<<(N_PTS * CHUNK) / 256, 256, 0, stream>>>(HH, pix, img, cb);
        pool_kernel<<<OW * OH, CHUNK, 0, stream>>>(img, out, cb);
    }
}

// Round 8
// 3015.107 us; speedup vs baseline: 1.2300x; 1.2300x over previous
//
#include <hip/hip_runtime.h>
#include <cstdint>

#define N_PTS 100000
#define N_EDGE 800000
#define N_ITEMS (N_EDGE + N_PTS)   // real edges + self-loops
#define IMG_W 1216
#define IMG_H 240
#define OW 304
#define OH 60
#define CHUNK 32
#define BIN_BLOCKS 391   // ceil(N_PTS/256)
#define SENT 0x7fffffff

typedef _Float16 f16;
typedef _Float16 f16x8 __attribute__((ext_vector_type(8)));
typedef float f32x4 __attribute__((ext_vector_type(4)));

__device__ __forceinline__ void ldsMaxF(float* addr, float v) {
    // float max via int max (v>=0) / uint min (v<0) on LDS; exact, order-independent
    if (v >= 0.0f) atomicMax((int*)addr, __float_as_int(v));
    else atomicMin((unsigned int*)addr, __float_as_uint(v));
}

// ---------------- per-node kernel: A[n] = X[n]@w1_x + pos[n]@w1_p + b1 (f16) ----------------
template<int DIN_X, int DOUT>
__global__ __launch_bounds__(256)
void node_kernel(const float* __restrict__ X, const float* __restrict__ pos,
                 const float* __restrict__ w1, const float* __restrict__ b1,
                 f16* __restrict__ A)
{
    constexpr int M = 8;
    constexpr int R = 256 / DOUT;
    constexpr int RR = (R < 1) ? 1 : R;
    constexpr int MN = M / RR;
    const int tid = threadIdx.x;
    const int c = tid % DOUT;
    const int r = tid / DOUT;
    const long n0 = (long)blockIdx.x * M;

    __shared__ float xs[M][DIN_X];
    __shared__ float ps[M][4];

    for (int idx = tid; idx < M * DIN_X; idx += 256) {
        int m = idx / DIN_X, k = idx % DIN_X;
        long n = n0 + m;
        xs[m][k] = (n < N_PTS) ? X[n * DIN_X + k] : 0.0f;
    }
    for (int idx = tid; idx < M * 3; idx += 256) {
        int m = idx / 3, k = idx % 3;
        long n = n0 + m;
        ps[m][k] = (n < N_PTS) ? pos[n * 3 + k] : 0.0f;
    }
    __syncthreads();

    float acc[MN];
#pragma unroll
    for (int mi = 0; mi < MN; ++mi) acc[mi] = b1[c];

    for (int k = 0; k < DIN_X; ++k) {
        float wv = w1[k * DOUT + c];
#pragma unroll
        for (int mi = 0; mi < MN; ++mi)
            acc[mi] += xs[r * MN + mi][k] * wv;
    }
#pragma unroll
    for (int k = 0; k < 3; ++k) {
        float wv = w1[(DIN_X + k) * DOUT + c];
#pragma unroll
        for (int mi = 0; mi < MN; ++mi)
            acc[mi] += ps[r * MN + mi][k] * wv;
    }
#pragma unroll
    for (int mi = 0; mi < MN; ++mi) {
        long n = n0 + r * MN + mi;
        if (n < N_PTS) A[n * DOUT + c] = (f16)acc[mi];
    }
}

// ---------------- w2 -> f16 transpose: w2t[n*D+k] = (f16)w2[k*D+n] ----------------
__global__ void cvt_w2(const float* __restrict__ w2, f16* __restrict__ w2t, int D)
{
    int i = blockIdx.x * 256 + threadIdx.x;
    if (i >= D * D) return;
    int n = i / D, k = i % D;
    w2t[i] = (f16)w2[k * D + n];
}

// ---------------- counting sort of (edges + self-loops) by dst ----------------
__global__ void init_hist_kernel(int* __restrict__ hist)
{
    int i = blockIdx.x * 256 + threadIdx.x;
    if (i < N_PTS) hist[i] = 1;   // self-loop
}

__global__ void hist_kernel(const int* __restrict__ ei, int* __restrict__ hist)
{
    int e = blockIdx.x * 256 + threadIdx.x;
    if (e < N_EDGE) atomicAdd(&hist[ei[N_EDGE + e]], 1);
}

__global__ void bsum_kernel(const int* __restrict__ hist, int* __restrict__ bsum)
{
    __shared__ int s[256];
    int i = blockIdx.x * 256 + threadIdx.x;
    s[threadIdx.x] = (i < N_PTS) ? hist[i] : 0;
    __syncthreads();
    for (int off = 128; off > 0; off >>= 1) {
        if (threadIdx.x < off) s[threadIdx.x] += s[threadIdx.x + off];
        __syncthreads();
    }
    if (threadIdx.x == 0) bsum[blockIdx.x] = s[0];
}

__global__ void scan_bsum_kernel(int* __restrict__ bsum)
{
    __shared__ int s[512];
    int t = threadIdx.x;
    int v = (t < BIN_BLOCKS) ? bsum[t] : 0;
    s[t] = v;
    __syncthreads();
    for (int off = 1; off < 512; off <<= 1) {
        int u = (t >= off) ? s[t - off] : 0;
        __syncthreads();
        s[t] += u;
        __syncthreads();
    }
    if (t < BIN_BLOCKS) bsum[t] = s[t] - v;   // exclusive
}

__global__ void rowptr_kernel(const int* __restrict__ hist, const int* __restrict__ bsum,
                              int* __restrict__ woff)
{
    __shared__ int s[256];
    int i = blockIdx.x * 256 + threadIdx.x;
    int v = (i < N_PTS) ? hist[i] : 0;
    s[threadIdx.x] = v;
    __syncthreads();
    for (int off = 1; off < 256; off <<= 1) {
        int u = (threadIdx.x >= off) ? s[threadIdx.x - off] : 0;
        __syncthreads();
        s[threadIdx.x] += u;
        __syncthreads();
    }
    if (i < N_PTS) woff[i] = bsum[blockIdx.x] + s[threadIdx.x] - v;  // exclusive
}

// scatter real edges and self-loops; afterwards woff[i] = row_ptr[i+1]
__global__ void scatter_edges_kernel(const int* __restrict__ ei, int* __restrict__ woff,
                                     int* __restrict__ srcS, int* __restrict__ dstS)
{
    int e = blockIdx.x * 256 + threadIdx.x;
    if (e >= N_ITEMS) return;
    int s, d;
    if (e < N_EDGE) { s = ei[e]; d = ei[N_EDGE + e]; }
    else            { s = d = e - N_EDGE; }
    int p = atomicAdd(&woff[d], 1);
    srcS[p] = s;
    dstS[p] = d;
}

// ---------------- MFMA message kernel with LDS max reduction (no global atomics) ---------
// Block owns 32 consecutive dsts; waves stream the block's contiguous sorted items
// (incl. self-loops) in 32-row MFMA windows. h = relu(A[src] - pos[dst]·w1p);
// g = h @ w2 + b2 via mfma_f32_16x16x32_f16; result max-reduced into a 32 x D
// LDS tile via ds-atomic max; final 32 x D coalesced plain stores.
// Fragment layouts: A row=lane&15, k=(lane>>4)*8+j ; B col=lane&15, same k ;
// C/D col=lane&15, row=(lane>>4)*4+reg.
template<int D>
__global__ __launch_bounds__(256)
void gemm_lds_kernel(const int* __restrict__ srcS, const int* __restrict__ dstS,
                     const int* __restrict__ rend,   // rend[i] = row_ptr[i+1]
                     const f16* __restrict__ A, const float* __restrict__ pos,
                     const float* __restrict__ w1p, const f16* __restrict__ w2t,
                     const float* __restrict__ b2, float* __restrict__ OUT)
{
    constexpr int KB = D / 32;
    constexpr int NB = D / 16;
    constexpr int LDR = D + 8;          // pad: stride mod 32 banks = 8 -> spreads kg groups
    __shared__ float smax[32 * LDR];

    const int tid = threadIdx.x;
    const int wave = tid >> 6;
    const int lane = tid & 63;
    const int row = lane & 15;
    const int kg = lane >> 4;
    const int g0 = blockIdx.x * 32;     // first owned dst
    const int start = (g0 == 0) ? 0 : rend[g0 - 1];
    const int end = rend[g0 + 31];

    for (int idx = tid; idx < 32 * D; idx += 256)
        smax[(idx / D) * LDR + (idx % D)] = -INFINITY;
    __syncthreads();

    for (int base = start + wave * 32; base < end; base += 128) {
        int sld[2], dcm[2];
        float qx[2], qy[2], qz[2];
#pragma unroll
        for (int mh = 0; mh < 2; ++mh) {
            int e = base + mh * 16 + row;
            bool ok = (e < end);
            sld[mh] = ok ? srcS[e] : 0;
            dcm[mh] = ok ? dstS[e] : SENT;
            int dsafe = ok ? dcm[mh] : g0;
            qx[mh] = pos[(long)dsafe * 3 + 0];
            qy[mh] = pos[(long)dsafe * 3 + 1];
            qz[mh] = pos[(long)dsafe * 3 + 2];
        }

        // A fragments in registers
        f16x8 pa[2][KB];
#pragma unroll
        for (int kb = 0; kb < KB; ++kb) {
            const int c0 = kb * 32 + kg * 8;
            f16x8 a0 = *(const f16x8*)&A[(long)sld[0] * D + c0];
            f16x8 a1 = *(const f16x8*)&A[(long)sld[1] * D + c0];
            f16x8 h0, h1;
#pragma unroll
            for (int j = 0; j < 8; ++j) {
                float wx = w1p[c0 + j];
                float wy = w1p[D + c0 + j];
                float wz = w1p[2 * D + c0 + j];
                h0[j] = (f16)fmaxf((float)a0[j] - (qx[0] * wx + qy[0] * wy + qz[0] * wz), 0.0f);
                h1[j] = (f16)fmaxf((float)a1[j] - (qx[1] * wx + qy[1] * wy + qz[1] * wz), 0.0f);
            }
            pa[0][kb] = h0;
            pa[1][kb] = h1;
        }

        // this lane's 8 output rows -> LDS rows (C/D layout: row = kg*4+reg)
        int lr0[4], lr1[4];
#pragma unroll
        for (int reg = 0; reg < 4; ++reg) {
            int d0 = __shfl(dcm[0], kg * 4 + reg);
            int d1 = __shfl(dcm[1], kg * 4 + reg);
            lr0[reg] = (d0 == SENT) ? -1 : (d0 - g0);
            lr1[reg] = (d1 == SENT) ? -1 : (d1 - g0);
        }

#pragma unroll
        for (int nb = 0; nb < NB; ++nb) {
            f32x4 acc0 = {0.0f, 0.0f, 0.0f, 0.0f};
            f32x4 acc1 = {0.0f, 0.0f, 0.0f, 0.0f};
#pragma unroll
            for (int kb = 0; kb < KB; ++kb) {
                f16x8 pb = *(const f16x8*)&w2t[(long)(nb * 16 + row) * D + kb * 32 + kg * 8];
                acc0 = __builtin_amdgcn_mfma_f32_16x16x32_f16(pa[0][kb], pb, acc0, 0, 0, 0);
                acc1 = __builtin_amdgcn_mfma_f32_16x16x32_f16(pa[1][kb], pb, acc1, 0, 0, 0);
            }
            const int col = nb * 16 + row;
            const float bb = b2[col];
#pragma unroll
            for (int reg = 0; reg < 4; ++reg) {
                if (lr0[reg] >= 0) ldsMaxF(&smax[lr0[reg] * LDR + col], acc0[reg] + bb);
                if (lr1[reg] >= 0) ldsMaxF(&smax[lr1[reg] * LDR + col], acc1[reg] + bb);
            }
        }
    }
    __syncthreads();

    for (int idx = tid; idx < 32 * D; idx += 256) {
        int d = idx / D, col = idx % D;
        OUT[(long)(g0 + d) * D + col] = smax[d * LDR + col];
    }
}

// ---------------- projection ----------------
__global__ void proj_kernel(const float* __restrict__ pos, const float* __restrict__ proj,
                            const int* __restrict__ img_h, const int* __restrict__ img_w,
                            int* __restrict__ pix)
{
    int n = blockIdx.x * blockDim.x + threadIdx.x;
    if (n >= N_PTS) return;
    float px = pos[n * 3 + 0], py = pos[n * 3 + 1], pz = pos[n * 3 + 2];
    float h0 = proj[0] * px + proj[1] * py + proj[2]  * pz + proj[3];
    float h1 = proj[4] * px + proj[5] * py + proj[6]  * pz + proj[7];
    float h2 = proj[8] * px + proj[9] * py + proj[10] * pz + proj[11];
    int off_u = img_w[0] - IMG_W;
    int off_v = img_h[0] - IMG_H;
    int ui = (int)(short)(h0 / h2) - off_u;   // int16 truncation semantics
    int vi = (int)(short)(h1 / h2) - off_v;
    bool valid = (ui >= 0) && (vi >= 0) && (ui < IMG_W) && (vi < IMG_H);
    pix[n] = valid ? (ui * IMG_H + vi) : -1;
}

// ---------------- scatter-add (pixel-major, CHUNK channels) ----------------
__global__ __launch_bounds__(256)
void scatter_kernel(const float* __restrict__ H, const int* __restrict__ pix,
                    float* __restrict__ img, int cbase)
{
    long g = (long)blockIdx.x * blockDim.x + threadIdx.x;
    if (g >= (long)N_PTS * CHUNK) return;
    int n = (int)(g / CHUNK);
    int c = (int)(g % CHUNK);
    int p = pix[n];
    if (p < 0) return;
    atomicAdd(&img[(long)p * CHUNK + c], H[(long)n * 256 + cbase + c]);
}

// ---------------- 4x4 max-pool ----------------
__global__ __launch_bounds__(CHUNK)
void pool_kernel(const float* __restrict__ img, float* __restrict__ out, int cbase)
{
    int cell = blockIdx.x;
    int wc = cell / OH, hc = cell % OH;
    int c = threadIdx.x;
    float mx = -INFINITY;
#pragma unroll
    for (int i = 0; i < 4; ++i)
#pragma unroll
        for (int j = 0; j < 4; ++j) {
            long p = (long)(wc * 4 + i) * IMG_H + (hc * 4 + j);
            mx = fmaxf(mx, img[p * CHUNK + c]);
        }
    out[(long)(cbase + c) * (OW * OH) + wc * OH + hc] = mx;
}

extern "C" void kernel_launch(void* const* d_in, const int* in_sizes, int n_in,
                              void* d_out, int out_size, void* d_ws, size_t ws_size,
                              hipStream_t stream)
{
    const float* x     = (const float*)d_in[0];
    const float* pos   = (const float*)d_in[1];
    const int*   ei    = (const int*)d_in[2];
    const float* proj  = (const float*)d_in[4];
    const int*   img_h = (const int*)d_in[5];
    const int*   img_w = (const int*)d_in[6];
    const float* w1_1 = (const float*)d_in[7];
    const float* b1_1 = (const float*)d_in[8];
    const float* w2_1 = (const float*)d_in[9];
    const float* b2_1 = (const float*)d_in[10];
    const float* w1_2 = (const float*)d_in[11];
    const float* b1_2 = (const float*)d_in[12];
    const float* w2_2 = (const float*)d_in[13];
    const float* b2_2 = (const float*)d_in[14];
    const float* w1_3 = (const float*)d_in[15];
    const float* b1_3 = (const float*)d_in[16];
    const float* w2_3 = (const float*)d_in[17];
    const float* b2_3 = (const float*)d_in[18];
    float* out = (float*)d_out;

    // ws layout (byte offsets), lifetime-aliased; peak = 162.3 MB (proven OK round 6/7)
    if (ws_size < 162300000ull) return;
    char* ws = (char*)d_ws;
    float* HH   = (float*)(ws + 0);
    float* F1   = (float*)(ws + 0);
    float* F0   = (float*)(ws + 51200000);
    f16*   A12  = (f16*)(ws + 76800000);
    f16*   A3   = (f16*)(ws + 102400000);
    float* img  = (float*)(ws + 102400000);
    int*   pix  = (int*)(ws + 153600000);
    f16*   w2t3 = (f16*)(ws + 154000000);
    f16*   w2t2 = (f16*)(ws + 154131072);
    f16*   w2t1 = (f16*)(ws + 154163840);
    int*   srcS = (int*)(ws + 154200000);
    int*   dstS = (int*)(ws + 157800000);
    int*   hist = (int*)(ws + 161400000);
    int*   woff = (int*)(ws + 161800000);
    int*   bsum = (int*)(ws + 162200000);

    const int NODE_BLOCKS = N_PTS / 8;            // 12500
    const int SEG_BLOCKS  = N_PTS / 32;           // 3125 (block owns 32 dsts)
    const int E256  = (N_EDGE + 255) / 256;       // 3125
    const int I256  = (N_ITEMS + 255) / 256;      // 3516

    // ---- sort (edges + self-loops) by dst; woff becomes row_ptr[i+1] ----
    init_hist_kernel<<<BIN_BLOCKS, 256, 0, stream>>>(hist);
    hist_kernel<<<E256, 256, 0, stream>>>(ei, hist);
    bsum_kernel<<<BIN_BLOCKS, 256, 0, stream>>>(hist, bsum);
    scan_bsum_kernel<<<1, 512, 0, stream>>>(bsum);
    rowptr_kernel<<<BIN_BLOCKS, 256, 0, stream>>>(hist, bsum, woff);
    scatter_edges_kernel<<<I256, 256, 0, stream>>>(ei, woff, srcS, dstS);

    // prep: transposed f16 weights + projection
    cvt_w2<<<(64 * 64 + 255) / 256, 256, 0, stream>>>(w2_1, w2t1, 64);
    cvt_w2<<<(128 * 128 + 255) / 256, 256, 0, stream>>>(w2_2, w2t2, 128);
    cvt_w2<<<(256 * 256 + 255) / 256, 256, 0, stream>>>(w2_3, w2t3, 256);
    proj_kernel<<<(N_PTS + 255) / 256, 256, 0, stream>>>(pos, proj, img_h, img_w, pix);

    // layer 1 (din 4 -> 64)
    node_kernel<4, 64><<<NODE_BLOCKS, 256, 0, stream>>>(x, pos, w1_1, b1_1, A12);
    gemm_lds_kernel<64><<<SEG_BLOCKS, 256, 0, stream>>>(srcS, dstS, woff, A12, pos, w1_1 + 4 * 64, w2t1, b2_1, F0);

    // layer 2 (64 -> 128)
    node_kernel<64, 128><<<NODE_BLOCKS, 256, 0, stream>>>(F0, pos, w1_2, b1_2, A12);
    gemm_lds_kernel<128><<<SEG_BLOCKS, 256, 0, stream>>>(srcS, dstS, woff, A12, pos, w1_2 + 64 * 128, w2t2, b2_2, F1);

    // layer 3 (128 -> 256)
    node_kernel<128, 256><<<NODE_BLOCKS, 256, 0, stream>>>(F1, pos, w1_3, b1_3, A3);
    gemm_lds_kernel<256><<<SEG_BLOCKS, 256, 0, stream>>>(srcS, dstS, woff, A3, pos, w1_3 + 128 * 256, w2t3, b2_3, HH);

    // scatter + pool in 32-channel chunks
    for (int cb = 0; cb < 256; cb += CHUNK) {
        hipMemsetAsync(img, 0, (size_t)IMG_W * IMG_H * CHUNK * 4, stream);
        scatter_kernel<<<(N_PTS * CHUNK) / 256, 256, 0, stream>>>(HH, pix, img, cb);
        pool_kernel<<<OW * OH, CHUNK, 0, stream>>>(img, out, cb);
    }
}

// Round 9
// 2338.167 us; speedup vs baseline: 1.5861x; 1.2895x over previous
//
#include <hip/hip_runtime.h>
#include <cstdint>

#define N_PTS 100000
#define N_EDGE 800000
#define N_ITEMS (N_EDGE + N_PTS)   // real edges + self-loops
#define IMG_W 1216
#define IMG_H 240
#define OW 304
#define OH 60
#define CHUNK 32
#define BIN_BLOCKS 391   // ceil(N_PTS/256)
#define SENT 0x7fffffff

typedef _Float16 f16;
typedef _Float16 f16x8 __attribute__((ext_vector_type(8)));
typedef float f32x4 __attribute__((ext_vector_type(4)));

// monotone float <-> u32 order-preserving map (max over u32 == max over float)
__device__ __forceinline__ unsigned encF(float f) {
    unsigned b = __float_as_uint(f);
    return b ^ (unsigned)(((int)b >> 31) | 0x80000000);
}
__device__ __forceinline__ float decF(unsigned u) {
    unsigned b = u ^ (unsigned)((~(int)u >> 31) | 0x80000000);
    return __uint_as_float(b);
}

// ---------------- per-node kernel: A[n] = X[n]@w1_x + pos[n]@w1_p + b1 (f16) ----------------
template<int DIN_X, int DOUT>
__global__ __launch_bounds__(256)
void node_kernel(const float* __restrict__ X, const float* __restrict__ pos,
                 const float* __restrict__ w1, const float* __restrict__ b1,
                 f16* __restrict__ A)
{
    constexpr int M = 8;
    constexpr int R = 256 / DOUT;
    constexpr int RR = (R < 1) ? 1 : R;
    constexpr int MN = M / RR;
    const int tid = threadIdx.x;
    const int c = tid % DOUT;
    const int r = tid / DOUT;
    const long n0 = (long)blockIdx.x * M;

    __shared__ float xs[M][DIN_X];
    __shared__ float ps[M][4];

    for (int idx = tid; idx < M * DIN_X; idx += 256) {
        int m = idx / DIN_X, k = idx % DIN_X;
        long n = n0 + m;
        xs[m][k] = (n < N_PTS) ? X[n * DIN_X + k] : 0.0f;
    }
    for (int idx = tid; idx < M * 3; idx += 256) {
        int m = idx / 3, k = idx % 3;
        long n = n0 + m;
        ps[m][k] = (n < N_PTS) ? pos[n * 3 + k] : 0.0f;
    }
    __syncthreads();

    float acc[MN];
#pragma unroll
    for (int mi = 0; mi < MN; ++mi) acc[mi] = b1[c];

    for (int k = 0; k < DIN_X; ++k) {
        float wv = w1[k * DOUT + c];
#pragma unroll
        for (int mi = 0; mi < MN; ++mi)
            acc[mi] += xs[r * MN + mi][k] * wv;
    }
#pragma unroll
    for (int k = 0; k < 3; ++k) {
        float wv = w1[(DIN_X + k) * DOUT + c];
#pragma unroll
        for (int mi = 0; mi < MN; ++mi)
            acc[mi] += ps[r * MN + mi][k] * wv;
    }
#pragma unroll
    for (int mi = 0; mi < MN; ++mi) {
        long n = n0 + r * MN + mi;
        if (n < N_PTS) A[n * DOUT + c] = (f16)acc[mi];
    }
}

// ---------------- w2 -> f16 transpose: w2t[n*D+k] = (f16)w2[k*D+n] ----------------
__global__ void cvt_w2(const float* __restrict__ w2, f16* __restrict__ w2t, int D)
{
    int i = blockIdx.x * 256 + threadIdx.x;
    if (i >= D * D) return;
    int n = i / D, k = i % D;
    w2t[i] = (f16)w2[k * D + n];
}

// ---------------- counting sort of (edges + self-loops) by dst ----------------
__global__ void init_hist_kernel(int* __restrict__ hist)
{
    int i = blockIdx.x * 256 + threadIdx.x;
    if (i < N_PTS) hist[i] = 1;   // self-loop
}

__global__ void hist_kernel(const int* __restrict__ ei, int* __restrict__ hist)
{
    int e = blockIdx.x * 256 + threadIdx.x;
    if (e < N_EDGE) atomicAdd(&hist[ei[N_EDGE + e]], 1);
}

__global__ void bsum_kernel(const int* __restrict__ hist, int* __restrict__ bsum)
{
    __shared__ int s[256];
    int i = blockIdx.x * 256 + threadIdx.x;
    s[threadIdx.x] = (i < N_PTS) ? hist[i] : 0;
    __syncthreads();
    for (int off = 128; off > 0; off >>= 1) {
        if (threadIdx.x < off) s[threadIdx.x] += s[threadIdx.x + off];
        __syncthreads();
    }
    if (threadIdx.x == 0) bsum[blockIdx.x] = s[0];
}

__global__ void scan_bsum_kernel(int* __restrict__ bsum)
{
    __shared__ int s[512];
    int t = threadIdx.x;
    int v = (t < BIN_BLOCKS) ? bsum[t] : 0;
    s[t] = v;
    __syncthreads();
    for (int off = 1; off < 512; off <<= 1) {
        int u = (t >= off) ? s[t - off] : 0;
        __syncthreads();
        s[t] += u;
        __syncthreads();
    }
    if (t < BIN_BLOCKS) bsum[t] = s[t] - v;   // exclusive
}

__global__ void rowptr_kernel(const int* __restrict__ hist, const int* __restrict__ bsum,
                              int* __restrict__ woff)
{
    __shared__ int s[256];
    int i = blockIdx.x * 256 + threadIdx.x;
    int v = (i < N_PTS) ? hist[i] : 0;
    s[threadIdx.x] = v;
    __syncthreads();
    for (int off = 1; off < 256; off <<= 1) {
        int u = (threadIdx.x >= off) ? s[threadIdx.x - off] : 0;
        __syncthreads();
        s[threadIdx.x] += u;
        __syncthreads();
    }
    if (i < N_PTS) woff[i] = bsum[blockIdx.x] + s[threadIdx.x] - v;  // exclusive
}

// scatter real edges and self-loops; afterwards woff[i] = row_ptr[i+1]
__global__ void scatter_edges_kernel(const int* __restrict__ ei, int* __restrict__ woff,
                                     int* __restrict__ srcS, int* __restrict__ dstS)
{
    int e = blockIdx.x * 256 + threadIdx.x;
    if (e >= N_ITEMS) return;
    int s, d;
    if (e < N_EDGE) { s = ei[e]; d = ei[N_EDGE + e]; }
    else            { s = d = e - N_EDGE; }
    int p = atomicAdd(&woff[d], 1);
    srcS[p] = s;
    dstS[p] = d;
}

// ---------------- MFMA message kernel with LDS max reduction (no global atomics) ---------
// Block owns 32 consecutive dsts; its 4 waves stream the contiguous sorted items
// (incl. self-loops) in 16-row MFMA windows. h = relu(A[src] - pos[dst]·w1p);
// g = h @ w2 + b2 via mfma_f32_16x16x32_f16; values reduced into a 32 x D u32 LDS
// tile via unconditional ds_max_u32 (monotone encode); final coalesced stores.
// Spill control: 16-row windows (pa[KB] = 32 VGPR max) + nb loop unroll capped at 2.
// Fragment layouts: A row=lane&15, k=(lane>>4)*8+j ; B col=lane&15, same k ;
// C/D col=lane&15, row=(lane>>4)*4+reg.
template<int D>
__global__ __launch_bounds__(256)
void gemm_lds_kernel(const int* __restrict__ srcS, const int* __restrict__ dstS,
                     const int* __restrict__ rend,   // rend[i] = row_ptr[i+1]
                     const f16* __restrict__ A, const float* __restrict__ pos,
                     const float* __restrict__ w1p, const f16* __restrict__ w2t,
                     const float* __restrict__ b2, float* __restrict__ OUT)
{
    constexpr int KB = D / 32;
    constexpr int NB = D / 16;
    constexpr int LDR = D + 8;          // stride mod 32 banks = 8 -> rows offset by 8 banks
    __shared__ unsigned smax[32 * LDR];

    const int tid = threadIdx.x;
    const int wave = tid >> 6;
    const int lane = tid & 63;
    const int row = lane & 15;
    const int kg = lane >> 4;
    const int g0 = blockIdx.x * 32;     // first owned dst
    const int start = (g0 == 0) ? 0 : rend[g0 - 1];
    const int end = rend[g0 + 31];

    for (int idx = tid; idx < 32 * LDR; idx += 256) smax[idx] = 0u;   // < encF(any real value)
    __syncthreads();

    for (int base = start + wave * 16; base < end; base += 64) {
        const int e = base + row;
        const bool ok = (e < end);
        const int sld = ok ? srcS[e] : 0;
        const int dcm = ok ? dstS[e] : SENT;
        const int dsafe = ok ? dcm : g0;
        const float qx = pos[(long)dsafe * 3 + 0];
        const float qy = pos[(long)dsafe * 3 + 1];
        const float qz = pos[(long)dsafe * 3 + 2];

        // A fragment for this lane's row (kg-th col slice)
        f16x8 pa[KB];
#pragma unroll
        for (int kb = 0; kb < KB; ++kb) {
            const int c0 = kb * 32 + kg * 8;
            f16x8 a = *(const f16x8*)&A[(long)sld * D + c0];
            f16x8 h;
#pragma unroll
            for (int j = 0; j < 8; ++j) {
                float wx = w1p[c0 + j];
                float wy = w1p[D + c0 + j];
                float wz = w1p[2 * D + c0 + j];
                h[j] = (f16)fmaxf((float)a[j] - (qx * wx + qy * wy + qz * wz), 0.0f);
            }
            pa[kb] = h;
        }

        // this lane's 4 output rows -> LDS row offsets (C/D layout: row = kg*4+reg)
        int lr[4];
#pragma unroll
        for (int reg = 0; reg < 4; ++reg) {
            int dd = __shfl(dcm, kg * 4 + reg);
            lr[reg] = (dd == SENT) ? -1 : (dd - g0) * LDR;
        }

#pragma unroll 2
        for (int nb = 0; nb < NB; ++nb) {
            f32x4 acc = {0.0f, 0.0f, 0.0f, 0.0f};
#pragma unroll
            for (int kb = 0; kb < KB; ++kb) {
                f16x8 pb = *(const f16x8*)&w2t[(long)(nb * 16 + row) * D + kb * 32 + kg * 8];
                acc = __builtin_amdgcn_mfma_f32_16x16x32_f16(pa[kb], pb, acc, 0, 0, 0);
            }
            const int col = nb * 16 + row;
            const float bb = b2[col];
#pragma unroll
            for (int reg = 0; reg < 4; ++reg) {
                if (lr[reg] >= 0)
                    atomicMax(&smax[lr[reg] + col], encF(acc[reg] + bb));
            }
        }
    }
    __syncthreads();

    for (int idx = tid; idx < 32 * D; idx += 256) {
        int d = idx / D, col = idx % D;
        OUT[(long)(g0 + d) * D + col] = decF(smax[d * LDR + col]);
    }
}

// ---------------- projection ----------------
__global__ void proj_kernel(const float* __restrict__ pos, const float* __restrict__ proj,
                            const int* __restrict__ img_h, const int* __restrict__ img_w,
                            int* __restrict__ pix)
{
    int n = blockIdx.x * blockDim.x + threadIdx.x;
    if (n >= N_PTS) return;
    float px = pos[n * 3 + 0], py = pos[n * 3 + 1], pz = pos[n * 3 + 2];
    float h0 = proj[0] * px + proj[1] * py + proj[2]  * pz + proj[3];
    float h1 = proj[4] * px + proj[5] * py + proj[6]  * pz + proj[7];
    float h2 = proj[8] * px + proj[9] * py + proj[10] * pz + proj[11];
    int off_u = img_w[0] - IMG_W;
    int off_v = img_h[0] - IMG_H;
    int ui = (int)(short)(h0 / h2) - off_u;   // int16 truncation semantics
    int vi = (int)(short)(h1 / h2) - off_v;
    bool valid = (ui >= 0) && (vi >= 0) && (ui < IMG_W) && (vi < IMG_H);
    pix[n] = valid ? (ui * IMG_H + vi) : -1;
}

// ---------------- scatter-add (pixel-major, CHUNK channels) ----------------
__global__ __launch_bounds__(256)
void scatter_kernel(const float* __restrict__ H, const int* __restrict__ pix,
                    float* __restrict__ img, int cbase)
{
    long g = (long)blockIdx.x * blockDim.x + threadIdx.x;
    if (g >= (long)N_PTS * CHUNK) return;
    int n = (int)(g / CHUNK);
    int c = (int)(g % CHUNK);
    int p = pix[n];
    if (p < 0) return;
    atomicAdd(&img[(long)p * CHUNK + c], H[(long)n * 256 + cbase + c]);
}

// ---------------- 4x4 max-pool ----------------
__global__ __launch_bounds__(CHUNK)
void pool_kernel(const float* __restrict__ img, float* __restrict__ out, int cbase)
{
    int cell = blockIdx.x;
    int wc = cell / OH, hc = cell % OH;
    int c = threadIdx.x;
    float mx = -INFINITY;
#pragma unroll
    for (int i = 0; i < 4; ++i)
#pragma unroll
        for (int j = 0; j < 4; ++j) {
            long p = (long)(wc * 4 + i) * IMG_H + (hc * 4 + j);
            mx = fmaxf(mx, img[p * CHUNK + c]);
        }
    out[(long)(cbase + c) * (OW * OH) + wc * OH + hc] = mx;
}

extern "C" void kernel_launch(void* const* d_in, const int* in_sizes, int n_in,
                              void* d_out, int out_size, void* d_ws, size_t ws_size,
                              hipStream_t stream)
{
    const float* x     = (const float*)d_in[0];
    const float* pos   = (const float*)d_in[1];
    const int*   ei    = (const int*)d_in[2];
    const float* proj  = (const float*)d_in[4];
    const int*   img_h = (const int*)d_in[5];
    const int*   img_w = (const int*)d_in[6];
    const float* w1_1 = (const float*)d_in[7];
    const float* b1_1 = (const float*)d_in[8];
    const float* w2_1 = (const float*)d_in[9];
    const float* b2_1 = (const float*)d_in[10];
    const float* w1_2 = (const float*)d_in[11];
    const float* b1_2 = (const float*)d_in[12];
    const float* w2_2 = (const float*)d_in[13];
    const float* b2_2 = (const float*)d_in[14];
    const float* w1_3 = (const float*)d_in[15];
    const float* b1_3 = (const float*)d_in[16];
    const float* w2_3 = (const float*)d_in[17];
    const float* b2_3 = (const float*)d_in[18];
    float* out = (float*)d_out;

    // ws layout (byte offsets), lifetime-aliased; peak = 162.3 MB (proven OK rounds 6-8)
    if (ws_size < 162300000ull) return;
    char* ws = (char*)d_ws;
    float* HH   = (float*)(ws + 0);
    float* F1   = (float*)(ws + 0);
    float* F0   = (float*)(ws + 51200000);
    f16*   A12  = (f16*)(ws + 76800000);
    f16*   A3   = (f16*)(ws + 102400000);
    float* img  = (float*)(ws + 102400000);
    int*   pix  = (int*)(ws + 153600000);
    f16*   w2t3 = (f16*)(ws + 154000000);
    f16*   w2t2 = (f16*)(ws + 154131072);
    f16*   w2t1 = (f16*)(ws + 154163840);
    int*   srcS = (int*)(ws + 154200000);
    int*   dstS = (int*)(ws + 157800000);
    int*   hist = (int*)(ws + 161400000);
    int*   woff = (int*)(ws + 161800000);
    int*   bsum = (int*)(ws + 162200000);

    const int NODE_BLOCKS = N_PTS / 8;            // 12500
    const int SEG_BLOCKS  = N_PTS / 32;           // 3125 (block owns 32 dsts)
    const int E256  = (N_EDGE + 255) / 256;       // 3125
    const int I256  = (N_ITEMS + 255) / 256;      // 3516

    // ---- sort (edges + self-loops) by dst; woff becomes row_ptr[i+1] ----
    init_hist_kernel<<<BIN_BLOCKS, 256, 0, stream>>>(hist);
    hist_kernel<<<E256, 256, 0, stream>>>(ei, hist);
    bsum_kernel<<<BIN_BLOCKS, 256, 0, stream>>>(hist, bsum);
    scan_bsum_kernel<<<1, 512, 0, stream>>>(bsum);
    rowptr_kernel<<<BIN_BLOCKS, 256, 0, stream>>>(hist, bsum, woff);
    scatter_edges_kernel<<<I256, 256, 0, stream>>>(ei, woff, srcS, dstS);

    // prep: transposed f16 weights + projection
    cvt_w2<<<(64 * 64 + 255) / 256, 256, 0, stream>>>(w2_1, w2t1, 64);
    cvt_w2<<<(128 * 128 + 255) / 256, 256, 0, stream>>>(w2_2, w2t2, 128);
    cvt_w2<<<(256 * 256 + 255) / 256, 256, 0, stream>>>(w2_3, w2t3, 256);
    proj_kernel<<<(N_PTS + 255) / 256, 256, 0, stream>>>(pos, proj, img_h, img_w, pix);

    // layer 1 (din 4 -> 64)
    node_kernel<4, 64><<<NODE_BLOCKS, 256, 0, stream>>>(x, pos, w1_1, b1_1, A12);
    gemm_lds_kernel<64><<<SEG_BLOCKS, 256, 0, stream>>>(srcS, dstS, woff, A12, pos, w1_1 + 4 * 64, w2t1, b2_1, F0);

    // layer 2 (64 -> 128)
    node_kernel<64, 128><<<NODE_BLOCKS, 256, 0, stream>>>(F0, pos, w1_2, b1_2, A12);
    gemm_lds_kernel<128><<<SEG_BLOCKS, 256, 0, stream>>>(srcS, dstS, woff, A12, pos, w1_2 + 64 * 128, w2t2, b2_2, F1);

    // layer 3 (128 -> 256)
    node_kernel<128, 256><<<NODE_BLOCKS, 256, 0, stream>>>(F1, pos, w1_3, b1_3, A3);
    gemm_lds_kernel<256><<<SEG_BLOCKS, 256, 0, stream>>>(srcS, dstS, woff, A3, pos, w1_3 + 128 * 256, w2t3, b2_3, HH);

    // scatter + pool in 32-channel chunks
    for (int cb = 0; cb < 256; cb += CHUNK) {
        hipMemsetAsync(img, 0, (size_t)IMG_W * IMG_H * CHUNK * 4, stream);
        scatter_kernel<<<(N_PTS * CHUNK) / 256, 256, 0, stream>>>(HH, pix, img, cb);
        pool_kernel<<<OW * OH, CHUNK, 0, stream>>>(img, out, cb);
    }
}

// Round 10
// 1786.818 us; speedup vs baseline: 2.0755x; 1.3086x over previous
//
#include <hip/hip_runtime.h>
#include <cstdint>

#define N_PTS 100000
#define N_EDGE 800000
#define N_ITEMS (N_EDGE + N_PTS)   // real edges + self-loops
#define IMG_W 1216
#define IMG_H 240
#define OW 304
#define OH 60
#define CHUNK 32
#define BIN_BLOCKS 391   // ceil(N_PTS/256)

typedef _Float16 f16;
typedef _Float16 f16x8 __attribute__((ext_vector_type(8)));
typedef float f32x4 __attribute__((ext_vector_type(4)));

__device__ __forceinline__ void atomicMaxF(float* addr, float v) {
    // float max via int max (v>=0) / uint min (v<0); exact, order-independent.
    // Works with init = -INFINITY (0xFF800000).
    if (v >= 0.0f) atomicMax((int*)addr, __float_as_int(v));
    else atomicMin((unsigned int*)addr, __float_as_uint(v));
}

// ---------------- init OUT to -inf ----------------
__global__ __launch_bounds__(256)
void init_out_kernel(float* __restrict__ p, long n)   // n multiple of 4
{
    long i = ((long)blockIdx.x * 256 + threadIdx.x) * 4;
    if (i < n) {
        float4 v = {-INFINITY, -INFINITY, -INFINITY, -INFINITY};
        *(float4*)&p[i] = v;
    }
}

// ---------------- MFMA node kernel: A[n] = [X|pos]@w1 + b1 (f16) ----------------
// A-frag row=lane&15, k=(lane>>4)*8+j ; B col=lane&15 same k ; C col=lane&15, row=kg*4+reg.
template<int DX, int KP, int D>
__global__ __launch_bounds__(256)
void node_mfma_kernel(const float* __restrict__ X, const float* __restrict__ pos,
                      const f16* __restrict__ w1t, const float* __restrict__ b1,
                      f16* __restrict__ A)
{
    constexpr int KB = KP / 32;
    constexpr int NB = D / 16;
    const int tid = threadIdx.x;
    const int wave = tid >> 6;
    const int lane = tid & 63;
    const int row = lane & 15;
    const int kg = lane >> 4;
    const int wbase = (blockIdx.x * 4 + wave) * 32;

    f16x8 pa[2][KB];
#pragma unroll
    for (int mh = 0; mh < 2; ++mh) {
        int n = wbase + mh * 16 + row;
        int ns = (n < N_PTS) ? n : 0;
#pragma unroll
        for (int kb = 0; kb < KB; ++kb) {
            const int c0 = kb * 32 + kg * 8;
            f16x8 h;
#pragma unroll
            for (int j = 0; j < 8; ++j) {
                int k = c0 + j;
                float v = 0.0f;
                if (k < DX) v = X[(long)ns * DX + k];
                else if (k < DX + 3) v = pos[(long)ns * 3 + (k - DX)];
                h[j] = (f16)v;
            }
            pa[mh][kb] = h;
        }
    }

#pragma unroll 2
    for (int nb = 0; nb < NB; ++nb) {
        f32x4 acc0 = {0.0f, 0.0f, 0.0f, 0.0f};
        f32x4 acc1 = {0.0f, 0.0f, 0.0f, 0.0f};
#pragma unroll
        for (int kb = 0; kb < KB; ++kb) {
            f16x8 pb = *(const f16x8*)&w1t[(long)(nb * 16 + row) * KP + kb * 32 + kg * 8];
            acc0 = __builtin_amdgcn_mfma_f32_16x16x32_f16(pa[0][kb], pb, acc0, 0, 0, 0);
            acc1 = __builtin_amdgcn_mfma_f32_16x16x32_f16(pa[1][kb], pb, acc1, 0, 0, 0);
        }
        const int col = nb * 16 + row;
        const float bb = b1[col];
#pragma unroll
        for (int reg = 0; reg < 4; ++reg) {
            int r = kg * 4 + reg;
            int n0 = wbase + r;
            int n1 = wbase + 16 + r;
            if (n0 < N_PTS) A[(long)n0 * D + col] = (f16)(acc0[reg] + bb);
            if (n1 < N_PTS) A[(long)n1 * D + col] = (f16)(acc1[reg] + bb);
        }
    }
}

// ---------------- weight prep ----------------
// w1t[c*KP+k] = (f16)w1[k*D+c], zero-padded to KP
__global__ void cvt_w1(const float* __restrict__ w1, f16* __restrict__ w1t,
                       int K, int KP, int D)
{
    int i = blockIdx.x * 256 + threadIdx.x;
    if (i >= D * KP) return;
    int c = i / KP, k = i % KP;
    w1t[i] = (k < K) ? (f16)w1[k * D + c] : (f16)0.0f;
}

// w2t[n*D+k] = (f16)w2[k*D+n]
__global__ void cvt_w2(const float* __restrict__ w2, f16* __restrict__ w2t, int D)
{
    int i = blockIdx.x * 256 + threadIdx.x;
    if (i >= D * D) return;
    int n = i / D, k = i % D;
    w2t[i] = (f16)w2[k * D + n];
}

// ---------------- counting sort of (edges + self-loops) by dst ----------------
__global__ void init_hist_kernel(int* __restrict__ hist)
{
    int i = blockIdx.x * 256 + threadIdx.x;
    if (i < N_PTS) hist[i] = 1;   // self-loop
}

__global__ void hist_kernel(const int* __restrict__ ei, int* __restrict__ hist)
{
    int e = blockIdx.x * 256 + threadIdx.x;
    if (e < N_EDGE) atomicAdd(&hist[ei[N_EDGE + e]], 1);
}

__global__ void bsum_kernel(const int* __restrict__ hist, int* __restrict__ bsum)
{
    __shared__ int s[256];
    int i = blockIdx.x * 256 + threadIdx.x;
    s[threadIdx.x] = (i < N_PTS) ? hist[i] : 0;
    __syncthreads();
    for (int off = 128; off > 0; off >>= 1) {
        if (threadIdx.x < off) s[threadIdx.x] += s[threadIdx.x + off];
        __syncthreads();
    }
    if (threadIdx.x == 0) bsum[blockIdx.x] = s[0];
}

__global__ void scan_bsum_kernel(int* __restrict__ bsum)
{
    __shared__ int s[512];
    int t = threadIdx.x;
    int v = (t < BIN_BLOCKS) ? bsum[t] : 0;
    s[t] = v;
    __syncthreads();
    for (int off = 1; off < 512; off <<= 1) {
        int u = (t >= off) ? s[t - off] : 0;
        __syncthreads();
        s[t] += u;
        __syncthreads();
    }
    if (t < BIN_BLOCKS) bsum[t] = s[t] - v;   // exclusive
}

__global__ void rowptr_kernel(const int* __restrict__ hist, const int* __restrict__ bsum,
                              int* __restrict__ woff)
{
    __shared__ int s[256];
    int i = blockIdx.x * 256 + threadIdx.x;
    int v = (i < N_PTS) ? hist[i] : 0;
    s[threadIdx.x] = v;
    __syncthreads();
    for (int off = 1; off < 256; off <<= 1) {
        int u = (threadIdx.x >= off) ? s[threadIdx.x - off] : 0;
        __syncthreads();
        s[threadIdx.x] += u;
        __syncthreads();
    }
    if (i < N_PTS) woff[i] = bsum[blockIdx.x] + s[threadIdx.x] - v;  // exclusive
}

__global__ void scatter_edges_kernel(const int* __restrict__ ei, int* __restrict__ woff,
                                     int* __restrict__ srcS, int* __restrict__ dstS)
{
    int e = blockIdx.x * 256 + threadIdx.x;
    if (e >= N_ITEMS) return;
    int s, d;
    if (e < N_EDGE) { s = ei[e]; d = ei[N_EDGE + e]; }
    else            { s = d = e - N_EDGE; }
    int p = atomicAdd(&woff[d], 1);
    srcS[p] = s;
    dstS[p] = d;
}

// ---------------- MFMA message kernel (dst-sorted items + run dedup) ----------------
// h[e][c] = relu(A[src_e][c] - pos[dst_e]·w1p[:,c]) ; g = h @ w2 + b2  (f16 MFMA)
// per-lane segmented suffix-max over its 4 contiguous sorted rows; one atomicMax
// per run-head into OUT (pre-initialized to -inf; self-loops are ordinary items).
// Fragment layouts: A row=lane&15, k=(lane>>4)*8+j ; B col=lane&15 same k ;
// C/D col=lane&15, row=(lane>>4)*4+reg.
template<int D>
__global__ __launch_bounds__(256)
void gemm_msg_kernel(const int* __restrict__ srcA, const int* __restrict__ dstA,
                     const f16* __restrict__ A, const float* __restrict__ pos,
                     const float* __restrict__ w1p, const f16* __restrict__ w2t,
                     const float* __restrict__ b2, float* __restrict__ OUT, int nItems)
{
    constexpr int KB = D / 32;
    constexpr int NB = D / 16;
    const int tid = threadIdx.x;
    const int wave = tid >> 6;
    const int lane = tid & 63;
    const int row = lane & 15;
    const int kg = lane >> 4;
    const long wbase = ((long)blockIdx.x * 4 + wave) * 32;

    int s[2], d[2];
    float px[2], py[2], pz[2];
#pragma unroll
    for (int mh = 0; mh < 2; ++mh) {
        long e = wbase + mh * 16 + row;
        bool ok = (e < nItems);
        int ss = ok ? srcA[e] : 0;
        int dd = ok ? dstA[e] : -1;
        s[mh] = ss; d[mh] = dd;
        int dsafe = ok ? dd : 0;
        px[mh] = pos[(long)dsafe * 3 + 0];
        py[mh] = pos[(long)dsafe * 3 + 1];
        pz[mh] = pos[(long)dsafe * 3 + 2];
    }

    // build A fragments in registers (no LDS)
    f16x8 pa[2][KB];
#pragma unroll
    for (int kb = 0; kb < KB; ++kb) {
        const int c0 = kb * 32 + kg * 8;
        f16x8 a0 = *(const f16x8*)&A[(long)s[0] * D + c0];
        f16x8 a1 = *(const f16x8*)&A[(long)s[1] * D + c0];
        f16x8 h0, h1;
#pragma unroll
        for (int j = 0; j < 8; ++j) {
            float wx = w1p[c0 + j];
            float wy = w1p[D + c0 + j];
            float wz = w1p[2 * D + c0 + j];
            h0[j] = (f16)fmaxf((float)a0[j] - (px[0] * wx + py[0] * wy + pz[0] * wz), 0.0f);
            h1[j] = (f16)fmaxf((float)a1[j] - (px[1] * wx + py[1] * wy + pz[1] * wz), 0.0f);
        }
        pa[0][kb] = h0;
        pa[1][kb] = h1;
    }

    // output rows handled by this lane: r = kg*4 + reg (C/D layout)
    int dd0[4], dd1[4];
#pragma unroll
    for (int reg = 0; reg < 4; ++reg) {
        int r = kg * 4 + reg;
        dd0[reg] = __shfl(d[0], r);
        dd1[reg] = __shfl(d[1], r);
    }
    // run-head flags (sorted dsts: equal-dst rows adjacent)
    bool hd0[4], hd1[4];
    hd0[0] = true; hd1[0] = true;
#pragma unroll
    for (int reg = 1; reg < 4; ++reg) {
        hd0[reg] = (dd0[reg] != dd0[reg - 1]);
        hd1[reg] = (dd1[reg] != dd1[reg - 1]);
    }

#pragma unroll
    for (int nb = 0; nb < NB; ++nb) {
        f32x4 acc0 = {0.0f, 0.0f, 0.0f, 0.0f};
        f32x4 acc1 = {0.0f, 0.0f, 0.0f, 0.0f};
#pragma unroll
        for (int kb = 0; kb < KB; ++kb) {
            f16x8 pb = *(const f16x8*)&w2t[(long)(nb * 16 + row) * D + kb * 32 + kg * 8];
            acc0 = __builtin_amdgcn_mfma_f32_16x16x32_f16(pa[0][kb], pb, acc0, 0, 0, 0);
            acc1 = __builtin_amdgcn_mfma_f32_16x16x32_f16(pa[1][kb], pb, acc1, 0, 0, 0);
        }
        const int col = nb * 16 + row;
        const float bb = b2[col];
        // segmented suffix-max over this lane's 4 rows, emit only at run heads
        float v0[4], v1[4];
#pragma unroll
        for (int reg = 0; reg < 4; ++reg) { v0[reg] = acc0[reg] + bb; v1[reg] = acc1[reg] + bb; }
        float s0[4], s1[4];
        s0[3] = v0[3]; s1[3] = v1[3];
#pragma unroll
        for (int reg = 2; reg >= 0; --reg) {
            s0[reg] = hd0[reg + 1] ? v0[reg] : fmaxf(v0[reg], s0[reg + 1]);
            s1[reg] = hd1[reg + 1] ? v1[reg] : fmaxf(v1[reg], s1[reg + 1]);
        }
#pragma unroll
        for (int reg = 0; reg < 4; ++reg) {
            if (hd0[reg] && dd0[reg] >= 0) atomicMaxF(&OUT[(long)dd0[reg] * D + col], s0[reg]);
            if (hd1[reg] && dd1[reg] >= 0) atomicMaxF(&OUT[(long)dd1[reg] * D + col], s1[reg]);
        }
    }
}

// ---------------- projection ----------------
__global__ void proj_kernel(const float* __restrict__ pos, const float* __restrict__ proj,
                            const int* __restrict__ img_h, const int* __restrict__ img_w,
                            int* __restrict__ pix)
{
    int n = blockIdx.x * blockDim.x + threadIdx.x;
    if (n >= N_PTS) return;
    float px = pos[n * 3 + 0], py = pos[n * 3 + 1], pz = pos[n * 3 + 2];
    float h0 = proj[0] * px + proj[1] * py + proj[2]  * pz + proj[3];
    float h1 = proj[4] * px + proj[5] * py + proj[6]  * pz + proj[7];
    float h2 = proj[8] * px + proj[9] * py + proj[10] * pz + proj[11];
    int off_u = img_w[0] - IMG_W;
    int off_v = img_h[0] - IMG_H;
    int ui = (int)(short)(h0 / h2) - off_u;   // int16 truncation semantics
    int vi = (int)(short)(h1 / h2) - off_v;
    bool valid = (ui >= 0) && (vi >= 0) && (ui < IMG_W) && (vi < IMG_H);
    pix[n] = valid ? (ui * IMG_H + vi) : -1;
}

// ---------------- scatter-add (pixel-major, CHUNK channels) ----------------
__global__ __launch_bounds__(256)
void scatter_kernel(const float* __restrict__ H, const int* __restrict__ pix,
                    float* __restrict__ img, int cbase)
{
    long g = (long)blockIdx.x * blockDim.x + threadIdx.x;
    if (g >= (long)N_PTS * CHUNK) return;
    int n = (int)(g / CHUNK);
    int c = (int)(g % CHUNK);
    int p = pix[n];
    if (p < 0) return;
    atomicAdd(&img[(long)p * CHUNK + c], H[(long)n * 256 + cbase + c]);
}

// ---------------- 4x4 max-pool ----------------
__global__ __launch_bounds__(CHUNK)
void pool_kernel(const float* __restrict__ img, float* __restrict__ out, int cbase)
{
    int cell = blockIdx.x;
    int wc = cell / OH, hc = cell % OH;
    int c = threadIdx.x;
    float mx = -INFINITY;
#pragma unroll
    for (int i = 0; i < 4; ++i)
#pragma unroll
        for (int j = 0; j < 4; ++j) {
            long p = (long)(wc * 4 + i) * IMG_H + (hc * 4 + j);
            mx = fmaxf(mx, img[p * CHUNK + c]);
        }
    out[(long)(cbase + c) * (OW * OH) + wc * OH + hc] = mx;
}

extern "C" void kernel_launch(void* const* d_in, const int* in_sizes, int n_in,
                              void* d_out, int out_size, void* d_ws, size_t ws_size,
                              hipStream_t stream)
{
    const float* x     = (const float*)d_in[0];
    const float* pos   = (const float*)d_in[1];
    const int*   ei    = (const int*)d_in[2];
    const float* proj  = (const float*)d_in[4];
    const int*   img_h = (const int*)d_in[5];
    const int*   img_w = (const int*)d_in[6];
    const float* w1_1 = (const float*)d_in[7];
    const float* b1_1 = (const float*)d_in[8];
    const float* w2_1 = (const float*)d_in[9];
    const float* b2_1 = (const float*)d_in[10];
    const float* w1_2 = (const float*)d_in[11];
    const float* b1_2 = (const float*)d_in[12];
    const float* w2_2 = (const float*)d_in[13];
    const float* b2_2 = (const float*)d_in[14];
    const float* w1_3 = (const float*)d_in[15];
    const float* b1_3 = (const float*)d_in[16];
    const float* w2_3 = (const float*)d_in[17];
    const float* b2_3 = (const float*)d_in[18];
    float* out = (float*)d_out;

    // ws layout (byte offsets), lifetime-aliased; peak = 162.4 MB:
    //   HH  @ 0 (102.4M) | F1 @ 0 (51.2M) | F0 @ 51.2M (25.6M) | A12 @ 76.8M (25.6M)
    //   A3 @ 102.4M (51.2M) | img @ 102.4M (37.4M, after edge3) | pix @ 153.6M
    //   w2t3 @ 154.0M | w2t2 @ 154,131,072 | w2t1 @ 154,163,840
    //   srcS @ 154.2M (3.6M) | dstS @ 157.8M (3.6M)
    //   hist @ 161.4M | woff @ 161.8M | bsum @ 162.2M
    //   w1t3 @ 162,210,000 (81,920) | w1t2 @ 162,300,000 (24,576) | w1t1 @ 162,330,000 (4,096)
    if (ws_size < 162400000ull) return;
    char* ws = (char*)d_ws;
    float* HH   = (float*)(ws + 0);
    float* F1   = (float*)(ws + 0);
    float* F0   = (float*)(ws + 51200000);
    f16*   A12  = (f16*)(ws + 76800000);
    f16*   A3   = (f16*)(ws + 102400000);
    float* img  = (float*)(ws + 102400000);
    int*   pix  = (int*)(ws + 153600000);
    f16*   w2t3 = (f16*)(ws + 154000000);
    f16*   w2t2 = (f16*)(ws + 154131072);
    f16*   w2t1 = (f16*)(ws + 154163840);
    int*   srcS = (int*)(ws + 154200000);
    int*   dstS = (int*)(ws + 157800000);
    int*   hist = (int*)(ws + 161400000);
    int*   woff = (int*)(ws + 161800000);
    int*   bsum = (int*)(ws + 162200000);
    f16*   w1t3 = (f16*)(ws + 162210000);
    f16*   w1t2 = (f16*)(ws + 162300000);
    f16*   w1t1 = (f16*)(ws + 162330000);

    const int NODE_BLOCKS = (N_PTS + 127) / 128;    // 782 (4 waves x 32 rows)
    const int EDGE_BLOCKS = (N_ITEMS + 127) / 128;  // 7032 (4 waves x 32 items)
    const int E256  = (N_EDGE + 255) / 256;         // 3125
    const int I256  = (N_ITEMS + 255) / 256;        // 3516

    // ---- sort (edges + self-loops) by dst ----
    init_hist_kernel<<<BIN_BLOCKS, 256, 0, stream>>>(hist);
    hist_kernel<<<E256, 256, 0, stream>>>(ei, hist);
    bsum_kernel<<<BIN_BLOCKS, 256, 0, stream>>>(hist, bsum);
    scan_bsum_kernel<<<1, 512, 0, stream>>>(bsum);
    rowptr_kernel<<<BIN_BLOCKS, 256, 0, stream>>>(hist, bsum, woff);
    scatter_edges_kernel<<<I256, 256, 0, stream>>>(ei, woff, srcS, dstS);

    // ---- weight prep + projection + output inits ----
    cvt_w1<<<(64 * 32 + 255) / 256, 256, 0, stream>>>(w1_1, w1t1, 7, 32, 64);
    cvt_w1<<<(128 * 96 + 255) / 256, 256, 0, stream>>>(w1_2, w1t2, 67, 96, 128);
    cvt_w1<<<(256 * 160 + 255) / 256, 256, 0, stream>>>(w1_3, w1t3, 131, 160, 256);
    cvt_w2<<<(64 * 64 + 255) / 256, 256, 0, stream>>>(w2_1, w2t1, 64);
    cvt_w2<<<(128 * 128 + 255) / 256, 256, 0, stream>>>(w2_2, w2t2, 128);
    cvt_w2<<<(256 * 256 + 255) / 256, 256, 0, stream>>>(w2_3, w2t3, 256);
    proj_kernel<<<(N_PTS + 255) / 256, 256, 0, stream>>>(pos, proj, img_h, img_w, pix);
    init_out_kernel<<<(N_PTS * 64 / 4 + 255) / 256, 256, 0, stream>>>(F0, (long)N_PTS * 64);
    init_out_kernel<<<(N_PTS * 128 / 4 + 255) / 256, 256, 0, stream>>>(F1, (long)N_PTS * 128);

    // layer 1 (din 4 -> 64)
    node_mfma_kernel<4, 32, 64><<<NODE_BLOCKS, 256, 0, stream>>>(x, pos, w1t1, b1_1, A12);
    gemm_msg_kernel<64><<<EDGE_BLOCKS, 256, 0, stream>>>(srcS, dstS, A12, pos, w1_1 + 4 * 64, w2t1, b2_1, F0, N_ITEMS);

    // layer 2 (64 -> 128)
    node_mfma_kernel<64, 96, 128><<<NODE_BLOCKS, 256, 0, stream>>>(F0, pos, w1t2, b1_2, A12);
    gemm_msg_kernel<128><<<EDGE_BLOCKS, 256, 0, stream>>>(srcS, dstS, A12, pos, w1_2 + 64 * 128, w2t2, b2_2, F1, N_ITEMS);

    // layer 3 (128 -> 256): node reads F1 (@0), THEN init HH (@0, overlaps F1)
    node_mfma_kernel<128, 160, 256><<<NODE_BLOCKS, 256, 0, stream>>>(F1, pos, w1t3, b1_3, A3);
    init_out_kernel<<<(N_PTS * 256 / 4 + 255) / 256, 256, 0, stream>>>(HH, (long)N_PTS * 256);
    gemm_msg_kernel<256><<<EDGE_BLOCKS, 256, 0, stream>>>(srcS, dstS, A3, pos, w1_3 + 128 * 256, w2t3, b2_3, HH, N_ITEMS);

    // scatter + pool in 32-channel chunks (img aliases A3 — after edge3 only)
    for (int cb = 0; cb < 256; cb += CHUNK) {
        hipMemsetAsync(img, 0, (size_t)IMG_W * IMG_H * CHUNK * 4, stream);
        scatter_kernel<<<(N_PTS * CHUNK) / 256, 256, 0, stream>>>(HH, pix, img, cb);
        pool_kernel<<<OW * OH, CHUNK, 0, stream>>>(img, out, cb);
    }
}